// Round 12
// baseline (31.118 us; speedup 1.0000x reference)
//
#include <hip/hip_runtime.h>

#define GAMMA_F 1.1f
#define F_DIM 5
#define BOXG 8
#define MAX_NSEG 256
#define MAXL 1024  // max points per segment (512 pairs)

__device__ __forceinline__ int prefix_lt(unsigned long long m) {
  return __builtin_amdgcn_mbcnt_hi(
      (unsigned)(m >> 32), __builtin_amdgcn_mbcnt_lo((unsigned)m, 0u));
}

// ---- Phase 1: block = 1 segment x 16 waves x 8 boxes each -----------------
// R8 structure; inner test replaced by margin test + exact fallback:
//   s_ref = fadd(fmul(dx,dx),fmul(dy,dy))  (reference chain, bit-exact)
//   t = fma(-2cx, x, fma(-2cy, y, q)),  q = fadd(fmul(x,x),fmul(y,y)) staged
//   |t - (s_ref - cx^2 - cy^2)| < 0.05  =>  t<=k-1 in, t>k+1 out, else exact
// Selected set always equals the reference set -> output bit-identical.
template <int NWAVE>
__global__ void __launch_bounds__(NWAVE * 64, 4) seg_lds_kernel(
    const float* __restrict__ pts, const float* __restrict__ boxes,
    int* __restrict__ cnt, unsigned short* __restrict__ idx, int N, int S,
    int NSEG, int L, int NGRP) {
  __shared__ __align__(16) float4 sp[MAXL / 2 + 64];  // (x0,x1,y0,y1) pairs
  __shared__ __align__(8) float2 sq[MAXL / 2 + 64];   // (q0,q1) pairs

  const int tid = threadIdx.x;
  const int lane = tid & 63;
  const int wid = tid >> 6;
  const int bpg = NGRP / NWAVE;  // blocks per segment
  const int seg = blockIdx.x / bpg;
  const int bg = blockIdx.x - seg * bpg;
  const int grp = bg * NWAVE + wid;
  const int box0 = grp * BOXG;

  const int start = seg * L;
  const int end = min(start + L, N);
  const int npts = end - start;  // even (N, L even)
  const int npair = npts >> 1;

  // Per-wave box params. smax = largest f32 s with sqrt_rn(s) <= r (exact,
  // proven R2). bxv/byv exact (x2 + negate). klo/khi via f64 with +-1 margin.
  float bxv[BOXG], byv[BOXG], klo[BOXG], khi[BOXG], smaxv[BOXG];
#pragma unroll
  for (int b = 0; b < BOXG; ++b) {
    const float* bx = boxes + (box0 + b) * 7;
    const float cx = bx[0];
    const float cy = bx[1];
    const float hdx = __fmul_rn(bx[3], 0.5f);
    const float hdy = __fmul_rn(bx[4], 0.5f);
    const float r = __fmul_rn(
        __fsqrt_rn(__fadd_rn(__fmul_rn(hdx, hdx), __fmul_rn(hdy, hdy))),
        GAMMA_F);
    const unsigned ru = __float_as_uint(r);
    const float rsucc = __uint_as_float(ru + 1u);        // r > 0, finite
    const double m = ((double)r + (double)rsucc) * 0.5;  // exact
    const double m2 = m * m;                             // exact
    const bool incl = ((ru & 1u) == 0u);  // RN tie-to-even lands on r
    const float c1 = (float)m2;
    const double c1d = (double)c1;
    const bool keep = incl ? (c1d <= m2) : (c1d < m2);
    const float smax = keep ? c1 : __uint_as_float(__float_as_uint(c1) - 1u);
    smaxv[b] = smax;
    bxv[b] = -2.0f * cx;  // exact
    byv[b] = -2.0f * cy;  // exact
    const double kd =
        (double)smax - (double)cx * (double)cx - (double)cy * (double)cy;
    klo[b] = (float)(kd - 1.0);
    khi[b] = (float)(kd + 1.0);
  }

  // Stage pairs: sp[t]=(x0,x1,y0,y1), sq[t]=(q0,q1), q=fadd(x*x,y*y).
  for (int t = tid; t < npair; t += NWAVE * 64) {
    const float* p0 = pts + (size_t)(start + 2 * t) * F_DIM;
    const float x0 = p0[0], y0 = p0[1];
    const float x1 = p0[F_DIM], y1 = p0[F_DIM + 1];
    sp[t] = make_float4(x0, x1, y0, y1);
    sq[t] = make_float2(__fadd_rn(__fmul_rn(x0, x0), __fmul_rn(y0, y0)),
                        __fadd_rn(__fmul_rn(x1, x1), __fmul_rn(y1, y1)));
  }
  __syncthreads();

  int c[BOXG];
#pragma unroll
  for (int b = 0; b < BOXG; ++b) c[b] = 0;

  const size_t ibase = ((size_t)box0 * NSEG + seg) * S;
  const int nfull = npts / 128;

#define PROCESS_8(RELBASE, QD, QQ, G0, G1)                                   \
  {                                                                          \
    const int rel = (RELBASE) + 2 * lane;                                    \
    _Pragma("unroll") for (int b = 0; b < BOXG; ++b) {                       \
      const float t0 = __builtin_fmaf(bxv[b], (QD).x,                        \
                                      __builtin_fmaf(byv[b], (QD).z, (QQ).x)); \
      const float t1 = __builtin_fmaf(bxv[b], (QD).y,                        \
                                      __builtin_fmaf(byv[b], (QD).w, (QQ).y)); \
      const bool in0 = (G0) && (t0 <= klo[b]);                               \
      const bool in1 = (G1) && (t1 <= klo[b]);                               \
      const bool may0 = (G0) && (t0 <= khi[b]);                              \
      const bool may1 = (G1) && (t1 <= khi[b]);                              \
      unsigned long long m0 = __ballot(in0);                                 \
      unsigned long long m1 = __ballot(in1);                                 \
      const unsigned long long M0 = __ballot(may0);                          \
      const unsigned long long M1 = __ballot(may1);                          \
      if ((M0 != m0) | (M1 != m1)) { /* rare: shell lanes -> exact */        \
        const float cx = __fmul_rn(bxv[b], -0.5f); /* exact recover */       \
        const float cy = __fmul_rn(byv[b], -0.5f);                           \
        const float dx0 = __fsub_rn((QD).x, cx);                             \
        const float dy0 = __fsub_rn((QD).z, cy);                             \
        const float s0 =                                                     \
            __fadd_rn(__fmul_rn(dx0, dx0), __fmul_rn(dy0, dy0));             \
        const float dx1 = __fsub_rn((QD).y, cx);                             \
        const float dy1 = __fsub_rn((QD).w, cy);                             \
        const float s1 =                                                     \
            __fadd_rn(__fmul_rn(dx1, dx1), __fmul_rn(dy1, dy1));             \
        m0 = __ballot((G0) && (s0 <= smaxv[b]));                             \
        m1 = __ballot((G1) && (s1 <= smaxv[b]));                             \
      }                                                                      \
      if (m0 | m1) {                                                         \
        const int p0 = prefix_lt(m0);                                        \
        const int p1 = prefix_lt(m1);                                        \
        const int r0 = c[b] + p0 + p1;                                       \
        const int r1 = c[b] + p0 + (int)((m0 >> lane) & 1ULL) + p1;          \
        unsigned short* mp = idx + ibase + (size_t)b * NSEG * S;             \
        if (((m0 >> lane) & 1ULL) && r0 < S) mp[r0] = (unsigned short)rel;   \
        if (((m1 >> lane) & 1ULL) && r1 < S)                                 \
          mp[r1] = (unsigned short)(rel + 1);                                \
        c[b] += __popcll(m0) + __popcll(m1);                                 \
      }                                                                      \
    }                                                                        \
  }

  for (int it = 0; it < nfull; ++it) {
    const float4 qd = sp[it * 64 + lane];  // ds_read_b128
    const float2 qq = sq[it * 64 + lane];  // ds_read_b64
    PROCESS_8(it * 128, qd, qq, true, true);
  }
  const int relb = nfull * 128;
  if (relb < npts) {
    const float4 qd = sp[nfull * 64 + lane];  // in-bounds (pad), masked
    const float2 qq = sq[nfull * 64 + lane];
    const int rel = relb + 2 * lane;
    const bool g0 = (rel < npts);
    const bool g1 = (rel + 1 < npts);
    PROCESS_8(relb, qd, qq, g0, g1);
  }
#undef PROCESS_8

  if (lane == 0) {
#pragma unroll
    for (int b = 0; b < BOXG; ++b) cnt[(box0 + b) * NSEG + seg] = min(c[b], S);
  }
}

// ------- Phase 2: per box, prefix over segment counts + gather features ------
__global__ void __launch_bounds__(256) gather_kernel(
    const float* __restrict__ pts, const int* __restrict__ cnt,
    const unsigned short* __restrict__ idx, float* __restrict__ out, int N,
    int S, int NSEG, int L) {
  const int b = blockIdx.x;
  const int tid = threadIdx.x;
  const int lane = tid & 63;
  const int wid = tid >> 6;

  __shared__ int pfx[MAX_NSEG + 1];
  __shared__ int wtot[4];
  __shared__ int woff[4];

  int v = (tid < NSEG) ? cnt[b * NSEG + tid] : 0;
  int sv = v;
#pragma unroll
  for (int d = 1; d < 64; d <<= 1) {
    const int t = __shfl_up(sv, d, 64);
    if (lane >= d) sv += t;
  }
  if (lane == 63) wtot[wid] = sv;
  __syncthreads();
  if (tid == 0) {
    int a = 0;
#pragma unroll
    for (int w = 0; w < 4; ++w) {
      woff[w] = a;
      a += wtot[w];
    }
  }
  __syncthreads();
  const int incl = sv + woff[wid];
  if (tid < NSEG) pfx[tid + 1] = incl;
  if (tid == 0) pfx[0] = 0;
  __syncthreads();

  const int total = pfx[NSEG];
  if (tid < S) {
    float* o = out + ((size_t)b * S + tid) * F_DIM;
    if (tid < total) {
      int lo = 0, hi = NSEG - 1;
      while (lo < hi) {
        const int mid = (lo + hi + 1) >> 1;
        if (pfx[mid] <= tid) lo = mid;
        else hi = mid - 1;
      }
      const int s = lo;
      const int gi =
          s * L + (int)idx[((size_t)b * NSEG + s) * S + (tid - pfx[s])];
      const float* p = pts + (size_t)gi * F_DIM;
      o[0] = p[0];
      o[1] = p[1];
      o[2] = p[2];
      o[3] = p[3];
      o[4] = p[4];
    } else {
      o[0] = 0.0f;
      o[1] = 0.0f;
      o[2] = 0.0f;
      o[3] = 0.0f;
      o[4] = 0.0f;
    }
  }
}

// ---------------- Fallback: proven R1 single-kernel version ----------------
template <int BLOCK>
__global__ void __launch_bounds__(BLOCK) voxel_sampler_fallback(
    const float* __restrict__ pts, const float* __restrict__ boxes,
    float* __restrict__ out, int N, int S) {
  constexpr int NW = BLOCK / 64;
  const int b = blockIdx.x;
  const int tid = threadIdx.x;
  const int lane = tid & 63;
  const int wid = tid >> 6;

  const float cx = boxes[b * 7 + 0];
  const float cy = boxes[b * 7 + 1];
  const float hdx = __fmul_rn(boxes[b * 7 + 3], 0.5f);
  const float hdy = __fmul_rn(boxes[b * 7 + 4], 0.5f);
  const float r = __fmul_rn(
      __fsqrt_rn(__fadd_rn(__fmul_rn(hdx, hdx), __fmul_rn(hdy, hdy))),
      GAMMA_F);

  __shared__ int s_wsum[NW];
  __shared__ int s_count;
  if (tid == 0) s_count = 0;
  __syncthreads();

  float* outb = out + (size_t)b * S * F_DIM;

  for (int base = 0; base < N; base += BLOCK) {
    const int i = base + tid;
    bool sel = false;
    float x = 0.0f, y = 0.0f;
    if (i < N) {
      x = pts[i * F_DIM + 0];
      y = pts[i * F_DIM + 1];
      const float ddx = __fsub_rn(x, cx);
      const float ddy = __fsub_rn(y, cy);
      const float dis =
          __fsqrt_rn(__fadd_rn(__fmul_rn(ddx, ddx), __fmul_rn(ddy, ddy)));
      sel = (dis <= r);
    }
    const unsigned long long m = __ballot(sel);
    if (lane == 0) s_wsum[wid] = __popcll(m);
    __syncthreads();
    const int cbase = s_count;
    int wbase = 0;
    int tot = 0;
#pragma unroll
    for (int w = 0; w < NW; ++w) {
      const int v = s_wsum[w];
      if (w < wid) wbase += v;
      tot += v;
    }
    const int pos = cbase + wbase + __popcll(m & ((1ULL << lane) - 1ULL));
    if (sel && pos < S) {
      float* o = outb + pos * F_DIM;
      o[0] = x;
      o[1] = y;
      o[2] = pts[i * F_DIM + 2];
      o[3] = pts[i * F_DIM + 3];
      o[4] = pts[i * F_DIM + 4];
    }
    __syncthreads();
    if (tid == 0) s_count = cbase + tot;
    __syncthreads();
    if (cbase + tot >= S) break;
  }

  __syncthreads();
  int cnt = s_count;
  if (cnt > S) cnt = S;
  for (int j = cnt * F_DIM + tid; j < S * F_DIM; j += BLOCK) outb[j] = 0.0f;
}

extern "C" void kernel_launch(void* const* d_in, const int* in_sizes, int n_in,
                              void* d_out, int out_size, void* d_ws,
                              size_t ws_size, hipStream_t stream) {
  const float* pts = (const float*)d_in[0];
  const float* boxes = (const float*)d_in[1];
  float* out = (float*)d_out;

  const int N = in_sizes[0] / F_DIM;     // 200000
  const int B = in_sizes[1] / 7;         // 256
  const int S = out_size / (B * F_DIM);  // 128

  const int NSEG = 256;
  int L = ((N + NSEG - 1) / NSEG + 1) & ~1;  // even
  const int NGRP = B / BOXG;                 // 32
  constexpr int NWAVE = 16;                  // 1024-thread blocks

  const size_t sz_cnt = (size_t)B * NSEG * sizeof(int);
  const size_t off_idx = (sz_cnt + 255) & ~(size_t)255;
  const size_t sz_idx = (size_t)B * NSEG * S * sizeof(unsigned short);
  const size_t need = off_idx + sz_idx;

  const bool fast = (ws_size >= need) && (L >= 2) && (L <= MAXL) &&
                    (L - 1 <= 65535) && (B % BOXG == 0) && (S <= 256) &&
                    (NSEG <= MAX_NSEG) && (NGRP % NWAVE == 0) &&
                    (N % 2 == 0) && ((size_t)L * NSEG >= (size_t)N);

  if (fast) {
    char* ws = (char*)d_ws;
    int* cnt = (int*)ws;
    unsigned short* idx = (unsigned short*)(ws + off_idx);

    const int bpg = NGRP / NWAVE;  // 2
    seg_lds_kernel<NWAVE><<<NSEG * bpg, NWAVE * 64, 0, stream>>>(
        pts, boxes, cnt, idx, N, S, NSEG, L, NGRP);
    gather_kernel<<<B, 256, 0, stream>>>(pts, cnt, idx, out, N, S, NSEG, L);
  } else {
    voxel_sampler_fallback<1024><<<B, 1024, 0, stream>>>(pts, boxes, out, N,
                                                         S);
  }
}

// Round 13
// 26.738 us; speedup vs baseline: 1.1638x; 1.1638x over previous
//
#include <hip/hip_runtime.h>

#define GAMMA_F 1.1f
#define F_DIM 5
#define BOXG 16
#define MAX_NSEG 256
#define MAXL 1024  // max points per segment (512 pairs, 8 KB LDS)

__device__ __forceinline__ int prefix_lt(unsigned long long m) {
  return __builtin_amdgcn_mbcnt_hi(
      (unsigned)(m >> 32), __builtin_amdgcn_mbcnt_lo((unsigned)m, 0u));
}

// ---- Phase 1: block = 1 segment x 16 waves x 16 boxes each (all 256). -----
// R8 inner loop byte-identical (scalar exact chain; 5/5 A/Bs says it's the
// best). Change vs R8: BOXG 8->16 => bpg=1, so each segment is staged into
// LDS by exactly ONE block (staging traffic halves from 2N to N).
// smax = largest f32 s with sqrt_rn(s) <= r (exact, proven R2).
template <int NWAVE>
__global__ void __launch_bounds__(NWAVE * 64, 4) seg_lds_kernel(
    const float* __restrict__ pts, const float* __restrict__ boxes,
    int* __restrict__ cnt, unsigned short* __restrict__ idx, int N, int S,
    int NSEG, int L, int NGRP) {
  __shared__ __align__(16) float2 sxy[MAXL];

  const int tid = threadIdx.x;
  const int lane = tid & 63;
  const int wid = tid >> 6;
  // bpg == 1: one block per segment; wave wid owns boxes [wid*16, wid*16+16).
  const int seg = blockIdx.x;
  const int grp = wid;
  const int box0 = grp * BOXG;

  const int start = seg * L;
  const int end = min(start + L, N);
  const int npts = end - start;

  // Per-wave box params (registers).
  float cx[BOXG], cy[BOXG], smax[BOXG];
#pragma unroll
  for (int b = 0; b < BOXG; ++b) {
    const float* bx = boxes + (box0 + b) * 7;
    cx[b] = bx[0];
    cy[b] = bx[1];
    const float hdx = __fmul_rn(bx[3], 0.5f);
    const float hdy = __fmul_rn(bx[4], 0.5f);
    const float r = __fmul_rn(
        __fsqrt_rn(__fadd_rn(__fmul_rn(hdx, hdx), __fmul_rn(hdy, hdy))),
        GAMMA_F);
    const unsigned ru = __float_as_uint(r);
    const float rsucc = __uint_as_float(ru + 1u);        // r > 0, finite
    const double m = ((double)r + (double)rsucc) * 0.5;  // exact
    const double m2 = m * m;                             // exact
    const bool incl = ((ru & 1u) == 0u);  // RN tie-to-even lands on r
    const float c1 = (float)m2;
    const double c1d = (double)c1;
    const bool keep = incl ? (c1d <= m2) : (c1d < m2);
    smax[b] = keep ? c1 : __uint_as_float(__float_as_uint(c1) - 1u);
  }

  // Stage this segment's xy into LDS (once per segment, single block).
  for (int t = tid; t < npts; t += NWAVE * 64) {
    const float* p = pts + (size_t)(start + t) * F_DIM;
    sxy[t] = make_float2(p[0], p[1]);
  }
  __syncthreads();

  int c[BOXG];
#pragma unroll
  for (int b = 0; b < BOXG; ++b) c[b] = 0;

  const size_t ibase = ((size_t)box0 * NSEG + seg) * S;
  const float4* sxy4 = (const float4*)sxy;

#define PROCESS_B(RELBASE, X0, Y0, X1, Y1, G0, G1)                          \
  {                                                                         \
    const int rel = (RELBASE) + 2 * lane;                                   \
    _Pragma("unroll") for (int b = 0; b < BOXG; ++b) {                      \
      const float dx0 = __fsub_rn((X0), cx[b]);                             \
      const float dy0 = __fsub_rn((Y0), cy[b]);                             \
      const float s0 = __fadd_rn(__fmul_rn(dx0, dx0), __fmul_rn(dy0, dy0)); \
      const float dx1 = __fsub_rn((X1), cx[b]);                             \
      const float dy1 = __fsub_rn((Y1), cy[b]);                             \
      const float s1 = __fadd_rn(__fmul_rn(dx1, dx1), __fmul_rn(dy1, dy1)); \
      const bool sel0 = (G0) && (s0 <= smax[b]);                            \
      const bool sel1 = (G1) && (s1 <= smax[b]);                            \
      const unsigned long long m0 = __ballot(sel0);                         \
      const unsigned long long m1 = __ballot(sel1);                         \
      if (m0 | m1) {                                                        \
        const int p0 = prefix_lt(m0);                                       \
        const int p1 = prefix_lt(m1);                                       \
        const int r0 = c[b] + p0 + p1;                                      \
        const int r1 = c[b] + p0 + (sel0 ? 1 : 0) + p1;                     \
        unsigned short* mp = idx + ibase + (size_t)b * NSEG * S;            \
        if (sel0 && r0 < S) mp[r0] = (unsigned short)rel;                   \
        if (sel1 && r1 < S) mp[r1] = (unsigned short)(rel + 1);             \
        c[b] += __popcll(m0) + __popcll(m1);                                \
      }                                                                     \
    }                                                                       \
  }

  const int nfull = npts / 128;
  for (int it = 0; it < nfull; ++it) {
    const float4 q = sxy4[it * 64 + lane];  // ds_read_b128, 2 points
    PROCESS_B(it * 128, q.x, q.y, q.z, q.w, true, true);
  }
  const int relb = nfull * 128;
  if (relb < npts) {
    const float4 q = sxy4[nfull * 64 + lane];  // in-bounds (MAXL), masked
    const int rel = relb + 2 * lane;
    const bool g0 = (rel < npts);
    const bool g1 = (rel + 1 < npts);
    PROCESS_B(relb, q.x, q.y, q.z, q.w, g0, g1);
  }
#undef PROCESS_B

  if (lane == 0) {
#pragma unroll
    for (int b = 0; b < BOXG; ++b) cnt[(box0 + b) * NSEG + seg] = min(c[b], S);
  }
}

// ------- Phase 2: per box, prefix over segment counts + gather features ------
__global__ void __launch_bounds__(256) gather_kernel(
    const float* __restrict__ pts, const int* __restrict__ cnt,
    const unsigned short* __restrict__ idx, float* __restrict__ out, int N,
    int S, int NSEG, int L) {
  const int b = blockIdx.x;
  const int tid = threadIdx.x;
  const int lane = tid & 63;
  const int wid = tid >> 6;

  __shared__ int pfx[MAX_NSEG + 1];
  __shared__ int wtot[4];
  __shared__ int woff[4];

  int v = (tid < NSEG) ? cnt[b * NSEG + tid] : 0;
  int sv = v;
#pragma unroll
  for (int d = 1; d < 64; d <<= 1) {
    const int t = __shfl_up(sv, d, 64);
    if (lane >= d) sv += t;
  }
  if (lane == 63) wtot[wid] = sv;
  __syncthreads();
  if (tid == 0) {
    int a = 0;
#pragma unroll
    for (int w = 0; w < 4; ++w) {
      woff[w] = a;
      a += wtot[w];
    }
  }
  __syncthreads();
  const int incl = sv + woff[wid];
  if (tid < NSEG) pfx[tid + 1] = incl;
  if (tid == 0) pfx[0] = 0;
  __syncthreads();

  const int total = pfx[NSEG];
  if (tid < S) {
    float* o = out + ((size_t)b * S + tid) * F_DIM;
    if (tid < total) {
      int lo = 0, hi = NSEG - 1;
      while (lo < hi) {
        const int mid = (lo + hi + 1) >> 1;
        if (pfx[mid] <= tid) lo = mid;
        else hi = mid - 1;
      }
      const int s = lo;
      const int gi =
          s * L + (int)idx[((size_t)b * NSEG + s) * S + (tid - pfx[s])];
      const float* p = pts + (size_t)gi * F_DIM;
      o[0] = p[0];
      o[1] = p[1];
      o[2] = p[2];
      o[3] = p[3];
      o[4] = p[4];
    } else {
      o[0] = 0.0f;
      o[1] = 0.0f;
      o[2] = 0.0f;
      o[3] = 0.0f;
      o[4] = 0.0f;
    }
  }
}

// ---------------- Fallback: proven R1 single-kernel version ----------------
template <int BLOCK>
__global__ void __launch_bounds__(BLOCK) voxel_sampler_fallback(
    const float* __restrict__ pts, const float* __restrict__ boxes,
    float* __restrict__ out, int N, int S) {
  constexpr int NW = BLOCK / 64;
  const int b = blockIdx.x;
  const int tid = threadIdx.x;
  const int lane = tid & 63;
  const int wid = tid >> 6;

  const float cx = boxes[b * 7 + 0];
  const float cy = boxes[b * 7 + 1];
  const float hdx = __fmul_rn(boxes[b * 7 + 3], 0.5f);
  const float hdy = __fmul_rn(boxes[b * 7 + 4], 0.5f);
  const float r = __fmul_rn(
      __fsqrt_rn(__fadd_rn(__fmul_rn(hdx, hdx), __fmul_rn(hdy, hdy))),
      GAMMA_F);

  __shared__ int s_wsum[NW];
  __shared__ int s_count;
  if (tid == 0) s_count = 0;
  __syncthreads();

  float* outb = out + (size_t)b * S * F_DIM;

  for (int base = 0; base < N; base += BLOCK) {
    const int i = base + tid;
    bool sel = false;
    float x = 0.0f, y = 0.0f;
    if (i < N) {
      x = pts[i * F_DIM + 0];
      y = pts[i * F_DIM + 1];
      const float ddx = __fsub_rn(x, cx);
      const float ddy = __fsub_rn(y, cy);
      const float dis =
          __fsqrt_rn(__fadd_rn(__fmul_rn(ddx, ddx), __fmul_rn(ddy, ddy)));
      sel = (dis <= r);
    }
    const unsigned long long m = __ballot(sel);
    if (lane == 0) s_wsum[wid] = __popcll(m);
    __syncthreads();
    const int cbase = s_count;
    int wbase = 0;
    int tot = 0;
#pragma unroll
    for (int w = 0; w < NW; ++w) {
      const int v = s_wsum[w];
      if (w < wid) wbase += v;
      tot += v;
    }
    const int pos = cbase + wbase + __popcll(m & ((1ULL << lane) - 1ULL));
    if (sel && pos < S) {
      float* o = outb + pos * F_DIM;
      o[0] = x;
      o[1] = y;
      o[2] = pts[i * F_DIM + 2];
      o[3] = pts[i * F_DIM + 3];
      o[4] = pts[i * F_DIM + 4];
    }
    __syncthreads();
    if (tid == 0) s_count = cbase + tot;
    __syncthreads();
    if (cbase + tot >= S) break;
  }

  __syncthreads();
  int cnt = s_count;
  if (cnt > S) cnt = S;
  for (int j = cnt * F_DIM + tid; j < S * F_DIM; j += BLOCK) outb[j] = 0.0f;
}

extern "C" void kernel_launch(void* const* d_in, const int* in_sizes, int n_in,
                              void* d_out, int out_size, void* d_ws,
                              size_t ws_size, hipStream_t stream) {
  const float* pts = (const float*)d_in[0];
  const float* boxes = (const float*)d_in[1];
  float* out = (float*)d_out;

  const int N = in_sizes[0] / F_DIM;     // 200000
  const int B = in_sizes[1] / 7;         // 256
  const int S = out_size / (B * F_DIM);  // 128

  const int NSEG = 256;
  int L = ((N + NSEG - 1) / NSEG + 1) & ~1;  // even
  const int NGRP = B / BOXG;                 // 16
  constexpr int NWAVE = 16;                  // 1024-thread blocks, bpg = 1

  const size_t sz_cnt = (size_t)B * NSEG * sizeof(int);
  const size_t off_idx = (sz_cnt + 255) & ~(size_t)255;
  const size_t sz_idx = (size_t)B * NSEG * S * sizeof(unsigned short);
  const size_t need = off_idx + sz_idx;

  const bool fast = (ws_size >= need) && (L >= 2) && (L <= MAXL) &&
                    (L - 1 <= 65535) && (B % BOXG == 0) && (S <= 256) &&
                    (NSEG <= MAX_NSEG) && (NGRP == NWAVE) &&
                    ((size_t)L * NSEG >= (size_t)N);

  if (fast) {
    char* ws = (char*)d_ws;
    int* cnt = (int*)ws;
    unsigned short* idx = (unsigned short*)(ws + off_idx);

    seg_lds_kernel<NWAVE><<<NSEG, NWAVE * 64, 0, stream>>>(
        pts, boxes, cnt, idx, N, S, NSEG, L, NGRP);
    gather_kernel<<<B, 256, 0, stream>>>(pts, cnt, idx, out, N, S, NSEG, L);
  } else {
    voxel_sampler_fallback<1024><<<B, 1024, 0, stream>>>(pts, boxes, out, N,
                                                         S);
  }
}

// Round 14
// 24.043 us; speedup vs baseline: 1.2943x; 1.1121x over previous
//
#include <hip/hip_runtime.h>

#define GAMMA_F 1.1f
#define F_DIM 5
#define BOXG 8
#define MAX_NSEG 256
#define MAXL 1024  // max points per segment staged in LDS (8 KB)

__device__ __forceinline__ int prefix_lt(unsigned long long m) {
  return __builtin_amdgcn_mbcnt_hi(
      (unsigned)(m >> 32), __builtin_amdgcn_mbcnt_lo((unsigned)m, 0u));
}

// ---- Phase 1: block = 1 segment x 16 waves x 8 boxes each (128 boxes). ----
// Best verified config (R8, 24.35us; 6 subsequent optimization attempts all
// null or regressed). Inner test s = fadd_rn(fmul_rn(dx,dx), fmul_rn(dy,dy))
// <= smax is bit-equivalent to the reference sqrt compare; smax = largest
// f32 s with sqrt_rn(s) <= r (exact, proven R2).
template <int NWAVE>
__global__ void __launch_bounds__(NWAVE * 64, 8) seg_lds_kernel(
    const float* __restrict__ pts, const float* __restrict__ boxes,
    int* __restrict__ cnt, unsigned short* __restrict__ idx, int N, int S,
    int NSEG, int L, int NGRP) {
  __shared__ __align__(16) float2 sxy[MAXL];

  const int tid = threadIdx.x;
  const int lane = tid & 63;
  const int wid = tid >> 6;
  const int bpg = NGRP / NWAVE;  // blocks per segment
  const int seg = blockIdx.x / bpg;
  const int bg = blockIdx.x - seg * bpg;
  const int grp = bg * NWAVE + wid;
  const int box0 = grp * BOXG;

  const int start = seg * L;
  const int end = min(start + L, N);
  const int npts = end - start;

  // Per-wave box params (registers).
  float cx[BOXG], cy[BOXG], smax[BOXG];
#pragma unroll
  for (int b = 0; b < BOXG; ++b) {
    const float* bx = boxes + (box0 + b) * 7;
    cx[b] = bx[0];
    cy[b] = bx[1];
    const float hdx = __fmul_rn(bx[3], 0.5f);
    const float hdy = __fmul_rn(bx[4], 0.5f);
    const float r = __fmul_rn(
        __fsqrt_rn(__fadd_rn(__fmul_rn(hdx, hdx), __fmul_rn(hdy, hdy))),
        GAMMA_F);
    const unsigned ru = __float_as_uint(r);
    const float rsucc = __uint_as_float(ru + 1u);        // r > 0, finite
    const double m = ((double)r + (double)rsucc) * 0.5;  // exact
    const double m2 = m * m;                             // exact
    const bool incl = ((ru & 1u) == 0u);  // RN tie-to-even lands on r
    const float c1 = (float)m2;
    const double c1d = (double)c1;
    const bool keep = incl ? (c1d <= m2) : (c1d < m2);
    smax[b] = keep ? c1 : __uint_as_float(__float_as_uint(c1) - 1u);
  }

  // Stage this segment's xy into LDS (once per block).
  for (int t = tid; t < npts; t += NWAVE * 64) {
    const float* p = pts + (size_t)(start + t) * F_DIM;
    sxy[t] = make_float2(p[0], p[1]);
  }
  __syncthreads();

  int c[BOXG];
#pragma unroll
  for (int b = 0; b < BOXG; ++b) c[b] = 0;

  const size_t ibase = ((size_t)box0 * NSEG + seg) * S;
  const float4* sxy4 = (const float4*)sxy;

#define PROCESS_8(RELBASE, X0, Y0, X1, Y1, G0, G1)                          \
  {                                                                         \
    const int rel = (RELBASE) + 2 * lane;                                   \
    _Pragma("unroll") for (int b = 0; b < BOXG; ++b) {                      \
      const float dx0 = __fsub_rn((X0), cx[b]);                             \
      const float dy0 = __fsub_rn((Y0), cy[b]);                             \
      const float s0 = __fadd_rn(__fmul_rn(dx0, dx0), __fmul_rn(dy0, dy0)); \
      const float dx1 = __fsub_rn((X1), cx[b]);                             \
      const float dy1 = __fsub_rn((Y1), cy[b]);                             \
      const float s1 = __fadd_rn(__fmul_rn(dx1, dx1), __fmul_rn(dy1, dy1)); \
      const bool sel0 = (G0) && (s0 <= smax[b]);                            \
      const bool sel1 = (G1) && (s1 <= smax[b]);                            \
      const unsigned long long m0 = __ballot(sel0);                         \
      const unsigned long long m1 = __ballot(sel1);                         \
      if (m0 | m1) {                                                        \
        const int p0 = prefix_lt(m0);                                       \
        const int p1 = prefix_lt(m1);                                       \
        const int r0 = c[b] + p0 + p1;                                      \
        const int r1 = c[b] + p0 + (sel0 ? 1 : 0) + p1;                     \
        unsigned short* mp = idx + ibase + (size_t)b * NSEG * S;            \
        if (sel0 && r0 < S) mp[r0] = (unsigned short)rel;                   \
        if (sel1 && r1 < S) mp[r1] = (unsigned short)(rel + 1);             \
        c[b] += __popcll(m0) + __popcll(m1);                                \
      }                                                                     \
    }                                                                       \
  }

  const int nfull = npts / 128;
  for (int it = 0; it < nfull; ++it) {
    const float4 q = sxy4[it * 64 + lane];  // ds_read_b128, 2 points
    PROCESS_8(it * 128, q.x, q.y, q.z, q.w, true, true);
  }
  const int relb = nfull * 128;
  if (relb < npts) {
    const float4 q = sxy4[nfull * 64 + lane];  // in-bounds (MAXL), masked
    const int rel = relb + 2 * lane;
    const bool g0 = (rel < npts);
    const bool g1 = (rel + 1 < npts);
    PROCESS_8(relb, q.x, q.y, q.z, q.w, g0, g1);
  }
#undef PROCESS_8

  if (lane == 0) {
#pragma unroll
    for (int b = 0; b < BOXG; ++b) cnt[(box0 + b) * NSEG + seg] = min(c[b], S);
  }
}

// ------- Phase 2: per box, prefix over segment counts + gather features ------
__global__ void __launch_bounds__(256) gather_kernel(
    const float* __restrict__ pts, const int* __restrict__ cnt,
    const unsigned short* __restrict__ idx, float* __restrict__ out, int N,
    int S, int NSEG, int L) {
  const int b = blockIdx.x;
  const int tid = threadIdx.x;
  const int lane = tid & 63;
  const int wid = tid >> 6;

  __shared__ int pfx[MAX_NSEG + 1];
  __shared__ int wtot[4];
  __shared__ int woff[4];

  int v = (tid < NSEG) ? cnt[b * NSEG + tid] : 0;
  int sv = v;
#pragma unroll
  for (int d = 1; d < 64; d <<= 1) {
    const int t = __shfl_up(sv, d, 64);
    if (lane >= d) sv += t;
  }
  if (lane == 63) wtot[wid] = sv;
  __syncthreads();
  if (tid == 0) {
    int a = 0;
#pragma unroll
    for (int w = 0; w < 4; ++w) {
      woff[w] = a;
      a += wtot[w];
    }
  }
  __syncthreads();
  const int incl = sv + woff[wid];
  if (tid < NSEG) pfx[tid + 1] = incl;
  if (tid == 0) pfx[0] = 0;
  __syncthreads();

  const int total = pfx[NSEG];
  if (tid < S) {
    float* o = out + ((size_t)b * S + tid) * F_DIM;
    if (tid < total) {
      int lo = 0, hi = NSEG - 1;
      while (lo < hi) {
        const int mid = (lo + hi + 1) >> 1;
        if (pfx[mid] <= tid) lo = mid;
        else hi = mid - 1;
      }
      const int s = lo;
      const int gi =
          s * L + (int)idx[((size_t)b * NSEG + s) * S + (tid - pfx[s])];
      const float* p = pts + (size_t)gi * F_DIM;
      o[0] = p[0];
      o[1] = p[1];
      o[2] = p[2];
      o[3] = p[3];
      o[4] = p[4];
    } else {
      o[0] = 0.0f;
      o[1] = 0.0f;
      o[2] = 0.0f;
      o[3] = 0.0f;
      o[4] = 0.0f;
    }
  }
}

// ---------------- Fallback: proven R1 single-kernel version ----------------
template <int BLOCK>
__global__ void __launch_bounds__(BLOCK) voxel_sampler_fallback(
    const float* __restrict__ pts, const float* __restrict__ boxes,
    float* __restrict__ out, int N, int S) {
  constexpr int NW = BLOCK / 64;
  const int b = blockIdx.x;
  const int tid = threadIdx.x;
  const int lane = tid & 63;
  const int wid = tid >> 6;

  const float cx = boxes[b * 7 + 0];
  const float cy = boxes[b * 7 + 1];
  const float hdx = __fmul_rn(boxes[b * 7 + 3], 0.5f);
  const float hdy = __fmul_rn(boxes[b * 7 + 4], 0.5f);
  const float r = __fmul_rn(
      __fsqrt_rn(__fadd_rn(__fmul_rn(hdx, hdx), __fmul_rn(hdy, hdy))),
      GAMMA_F);

  __shared__ int s_wsum[NW];
  __shared__ int s_count;
  if (tid == 0) s_count = 0;
  __syncthreads();

  float* outb = out + (size_t)b * S * F_DIM;

  for (int base = 0; base < N; base += BLOCK) {
    const int i = base + tid;
    bool sel = false;
    float x = 0.0f, y = 0.0f;
    if (i < N) {
      x = pts[i * F_DIM + 0];
      y = pts[i * F_DIM + 1];
      const float ddx = __fsub_rn(x, cx);
      const float ddy = __fsub_rn(y, cy);
      const float dis =
          __fsqrt_rn(__fadd_rn(__fmul_rn(ddx, ddx), __fmul_rn(ddy, ddy)));
      sel = (dis <= r);
    }
    const unsigned long long m = __ballot(sel);
    if (lane == 0) s_wsum[wid] = __popcll(m);
    __syncthreads();
    const int cbase = s_count;
    int wbase = 0;
    int tot = 0;
#pragma unroll
    for (int w = 0; w < NW; ++w) {
      const int v = s_wsum[w];
      if (w < wid) wbase += v;
      tot += v;
    }
    const int pos = cbase + wbase + __popcll(m & ((1ULL << lane) - 1ULL));
    if (sel && pos < S) {
      float* o = outb + pos * F_DIM;
      o[0] = x;
      o[1] = y;
      o[2] = pts[i * F_DIM + 2];
      o[3] = pts[i * F_DIM + 3];
      o[4] = pts[i * F_DIM + 4];
    }
    __syncthreads();
    if (tid == 0) s_count = cbase + tot;
    __syncthreads();
    if (cbase + tot >= S) break;
  }

  __syncthreads();
  int cnt = s_count;
  if (cnt > S) cnt = S;
  for (int j = cnt * F_DIM + tid; j < S * F_DIM; j += BLOCK) outb[j] = 0.0f;
}

extern "C" void kernel_launch(void* const* d_in, const int* in_sizes, int n_in,
                              void* d_out, int out_size, void* d_ws,
                              size_t ws_size, hipStream_t stream) {
  const float* pts = (const float*)d_in[0];
  const float* boxes = (const float*)d_in[1];
  float* out = (float*)d_out;

  const int N = in_sizes[0] / F_DIM;     // 200000
  const int B = in_sizes[1] / 7;         // 256
  const int S = out_size / (B * F_DIM);  // 128

  const int NSEG = 256;
  int L = ((N + NSEG - 1) / NSEG + 1) & ~1;  // even
  const int NGRP = B / BOXG;                 // 32
  constexpr int NWAVE = 16;                  // 1024-thread blocks

  const size_t sz_cnt = (size_t)B * NSEG * sizeof(int);
  const size_t off_idx = (sz_cnt + 255) & ~(size_t)255;
  const size_t sz_idx = (size_t)B * NSEG * S * sizeof(unsigned short);
  const size_t need = off_idx + sz_idx;

  const bool fast = (ws_size >= need) && (L >= 2) && (L <= MAXL) &&
                    (L - 1 <= 65535) && (B % BOXG == 0) && (S <= 256) &&
                    (NSEG <= MAX_NSEG) && (NGRP % NWAVE == 0) &&
                    ((size_t)L * NSEG >= (size_t)N);

  if (fast) {
    char* ws = (char*)d_ws;
    int* cnt = (int*)ws;
    unsigned short* idx = (unsigned short*)(ws + off_idx);

    const int bpg = NGRP / NWAVE;  // 2
    seg_lds_kernel<NWAVE><<<NSEG * bpg, NWAVE * 64, 0, stream>>>(
        pts, boxes, cnt, idx, N, S, NSEG, L, NGRP);
    gather_kernel<<<B, 256, 0, stream>>>(pts, cnt, idx, out, N, S, NSEG, L);
  } else {
    voxel_sampler_fallback<1024><<<B, 1024, 0, stream>>>(pts, boxes, out, N,
                                                         S);
  }
}